// Round 1
// baseline (285.928 us; speedup 1.0000x reference)
//
#include <hip/hip_runtime.h>

// BCE with per-class weights, reduced to a scalar.
// pred,true: (B=2, C=16, D=64, H=128, W=128) fp32; weight: (16,) fp32.
// final = sum_e w[c(e)] * bce_e / (B*D*H*W * sum(w))
// Memory-bound: 268 MB read -> ~43 us at 6.3 TB/s.

static constexpr int kTotal = 2 * 16 * 64 * 128 * 128;  // 33,554,432
static constexpr int kN4 = kTotal / 4;                  // 8,388,608 float4s
static constexpr float kPerClassN = 2097152.0f;         // B*D*H*W = 2^21

__global__ __launch_bounds__(256) void bce_reduce_kernel(
    const float4* __restrict__ pred, const float4* __restrict__ tru,
    const float* __restrict__ weight, float* __restrict__ acc_out) {
  const int tid = blockIdx.x * 256 + threadIdx.x;
  const int stride = gridDim.x * 256;

  float acc = 0.0f;
  for (int i = tid; i < kN4; i += stride) {
    const float4 p = pred[i];
    const float4 t = tru[i];
    // element index e = 4*i; class c = (e >> 20) & 15 = (i >> 18) & 15
    const float w = weight[(i >> 18) & 15];

    float s = 0.0f;
    {
      const float lp = fmaxf(__logf(p.x), -100.0f);
      const float l1 = fmaxf(__logf(1.0f - p.x), -100.0f);
      s += l1 + t.x * (lp - l1);  // = t*lp + (1-t)*l1
    }
    {
      const float lp = fmaxf(__logf(p.y), -100.0f);
      const float l1 = fmaxf(__logf(1.0f - p.y), -100.0f);
      s += l1 + t.y * (lp - l1);
    }
    {
      const float lp = fmaxf(__logf(p.z), -100.0f);
      const float l1 = fmaxf(__logf(1.0f - p.z), -100.0f);
      s += l1 + t.z * (lp - l1);
    }
    {
      const float lp = fmaxf(__logf(p.w), -100.0f);
      const float l1 = fmaxf(__logf(1.0f - p.w), -100.0f);
      s += l1 + t.w * (lp - l1);
    }
    acc -= w * s;  // bce = -(t*lp + (1-t)*l1), weighted
  }

  // wave(64) shuffle reduction
  #pragma unroll
  for (int off = 32; off > 0; off >>= 1) acc += __shfl_down(acc, off, 64);

  __shared__ float smem[4];  // 256 threads = 4 waves
  const int lane = threadIdx.x & 63;
  const int wv = threadIdx.x >> 6;
  if (lane == 0) smem[wv] = acc;
  __syncthreads();
  if (threadIdx.x == 0) {
    const float blocksum = smem[0] + smem[1] + smem[2] + smem[3];
    atomicAdd(acc_out, blocksum);
  }
}

__global__ void bce_finalize_kernel(const float* __restrict__ weight,
                                    const float* __restrict__ acc,
                                    float* __restrict__ out) {
  if (threadIdx.x == 0) {
    float sw = 0.0f;
    #pragma unroll
    for (int c = 0; c < 16; ++c) sw += weight[c];
    out[0] = acc[0] / (kPerClassN * sw);
  }
}

extern "C" void kernel_launch(void* const* d_in, const int* in_sizes, int n_in,
                              void* d_out, int out_size, void* d_ws, size_t ws_size,
                              hipStream_t stream) {
  const float4* pred = (const float4*)d_in[0];
  const float4* tru = (const float4*)d_in[1];
  const float* weight = (const float*)d_in[2];
  float* out = (float*)d_out;
  float* acc = (float*)d_ws;  // one float accumulator in workspace

  hipMemsetAsync(acc, 0, sizeof(float), stream);  // d_ws is poisoned each call

  // 2048 blocks x 256 threads = 524,288 threads -> exactly 16 float4 iters each.
  bce_reduce_kernel<<<2048, 256, 0, stream>>>(pred, tru, weight, acc);
  bce_finalize_kernel<<<1, 64, 0, stream>>>(weight, acc, out);
}

// Round 2
// 280.395 us; speedup vs baseline: 1.0197x; 1.0197x over previous
//
#include <hip/hip_runtime.h>

// BCE with per-class weights, reduced to a scalar.
// pred,true: (B=2, C=16, D=64, H=128, W=128) fp32; weight: (16,) fp32.
// final = sum_e w[c(e)] * bce_e / (B*D*H*W * sum(w))
// Memory-bound: 268 MB read -> ~43 us at 6.3 TB/s achievable.
//
// R1: block-contiguous tiles. Each block owns 4096 consecutive float4s
// (64 KB per tensor). Class chunks are 2^18 float4s = 64 blocks, so each
// block has exactly ONE class -> weight is a scalar (SGPR) load, applied
// once in the epilogue. Known trip count + unroll(4) lets the compiler
// keep ~8 float4 loads in flight per wave instead of a vmcnt(0) round
// trip every iteration.

static constexpr int kTotal = 2 * 16 * 64 * 128 * 128;  // 33,554,432
static constexpr int kN4 = kTotal / 4;                  // 8,388,608 float4s
static constexpr int kBlocks = 2048;
static constexpr int kPerBlock4 = kN4 / kBlocks;        // 4096 float4s/block
static constexpr float kPerClassN = 2097152.0f;         // B*D*H*W = 2^21

__global__ __launch_bounds__(256) void bce_reduce_kernel(
    const float4* __restrict__ pred, const float4* __restrict__ tru,
    const float* __restrict__ weight, float* __restrict__ acc_out) {
  const int base = blockIdx.x * kPerBlock4;
  // class = (element_index >> 20) & 15 = (float4_index >> 18) & 15
  //       = (blockIdx.x >> 6) & 15  -- uniform across the block (SGPR).
  const float w = weight[(blockIdx.x >> 6) & 15];

  float acc = 0.0f;  // accumulates t*lp + (1-t)*l1 (un-negated, un-weighted)
  #pragma unroll 4
  for (int k = 0; k < 16; ++k) {
    const int i = base + (k << 8) + (int)threadIdx.x;
    const float4 p = pred[i];
    const float4 t = tru[i];
    {
      const float lp = fmaxf(__logf(p.x), -100.0f);
      const float l1 = fmaxf(__logf(1.0f - p.x), -100.0f);
      acc += l1 + t.x * (lp - l1);
    }
    {
      const float lp = fmaxf(__logf(p.y), -100.0f);
      const float l1 = fmaxf(__logf(1.0f - p.y), -100.0f);
      acc += l1 + t.y * (lp - l1);
    }
    {
      const float lp = fmaxf(__logf(p.z), -100.0f);
      const float l1 = fmaxf(__logf(1.0f - p.z), -100.0f);
      acc += l1 + t.z * (lp - l1);
    }
    {
      const float lp = fmaxf(__logf(p.w), -100.0f);
      const float l1 = fmaxf(__logf(1.0f - p.w), -100.0f);
      acc += l1 + t.w * (lp - l1);
    }
  }

  // wave(64) shuffle reduction
  #pragma unroll
  for (int off = 32; off > 0; off >>= 1) acc += __shfl_down(acc, off, 64);

  __shared__ float smem[4];  // 256 threads = 4 waves
  const int lane = threadIdx.x & 63;
  const int wv = threadIdx.x >> 6;
  if (lane == 0) smem[wv] = acc;
  __syncthreads();
  if (threadIdx.x == 0) {
    const float blocksum = smem[0] + smem[1] + smem[2] + smem[3];
    atomicAdd(acc_out, -w * blocksum);  // bce = -(...), weighted per block
  }
}

__global__ void bce_finalize_kernel(const float* __restrict__ weight,
                                    const float* __restrict__ acc,
                                    float* __restrict__ out) {
  if (threadIdx.x == 0) {
    float sw = 0.0f;
    #pragma unroll
    for (int c = 0; c < 16; ++c) sw += weight[c];
    out[0] = acc[0] / (kPerClassN * sw);
  }
}

extern "C" void kernel_launch(void* const* d_in, const int* in_sizes, int n_in,
                              void* d_out, int out_size, void* d_ws, size_t ws_size,
                              hipStream_t stream) {
  const float4* pred = (const float4*)d_in[0];
  const float4* tru = (const float4*)d_in[1];
  const float* weight = (const float*)d_in[2];
  float* out = (float*)d_out;
  float* acc = (float*)d_ws;  // one float accumulator in workspace

  hipMemsetAsync(acc, 0, sizeof(float), stream);  // d_ws is poisoned each call

  bce_reduce_kernel<<<kBlocks, 256, 0, stream>>>(pred, tru, weight, acc);
  bce_finalize_kernel<<<1, 64, 0, stream>>>(weight, acc, out);
}

// Round 3
// 279.035 us; speedup vs baseline: 1.0247x; 1.0049x over previous
//
#include <hip/hip_runtime.h>

// BCE with per-class weights, reduced to a scalar.
// pred,true: (B=2, C=16, D=64, H=128, W=128) fp32; weight: (16,) fp32.
// final = sum_e w[c(e)] * bce_e / (B*D*H*W * sum(w))
// Memory-bound roofline: 268 MB read -> ~43 us at 6.3 TB/s achievable.
//
// R1: block-contiguous 64KB tiles, per-block class weight in SGPR.
// R2: replace 2048 same-address device atomicAdds (cross-XCD serialized
//     RMW ~ the 60 us gap) with per-block partial stores to d_ws +
//     a 1-block reduce/finalize kernel. Loop body identical to R1.

static constexpr int kTotal = 2 * 16 * 64 * 128 * 128;  // 33,554,432
static constexpr int kN4 = kTotal / 4;                  // 8,388,608 float4s
static constexpr int kBlocks = 2048;
static constexpr int kPerBlock4 = kN4 / kBlocks;        // 4096 float4s/block
static constexpr float kPerClassN = 2097152.0f;         // B*D*H*W = 2^21

__global__ __launch_bounds__(256) void bce_reduce_kernel(
    const float4* __restrict__ pred, const float4* __restrict__ tru,
    const float* __restrict__ weight, float* __restrict__ partials) {
  const int base = blockIdx.x * kPerBlock4;
  // class = (float4_index >> 18) & 15 = (blockIdx.x >> 6) & 15 (block-uniform)
  const float w = weight[(blockIdx.x >> 6) & 15];

  float acc = 0.0f;  // accumulates t*lp + (1-t)*l1 (un-negated, un-weighted)
  #pragma unroll 4
  for (int k = 0; k < 16; ++k) {
    const int i = base + (k << 8) + (int)threadIdx.x;
    const float4 p = pred[i];
    const float4 t = tru[i];
    {
      const float lp = fmaxf(__logf(p.x), -100.0f);
      const float l1 = fmaxf(__logf(1.0f - p.x), -100.0f);
      acc += l1 + t.x * (lp - l1);
    }
    {
      const float lp = fmaxf(__logf(p.y), -100.0f);
      const float l1 = fmaxf(__logf(1.0f - p.y), -100.0f);
      acc += l1 + t.y * (lp - l1);
    }
    {
      const float lp = fmaxf(__logf(p.z), -100.0f);
      const float l1 = fmaxf(__logf(1.0f - p.z), -100.0f);
      acc += l1 + t.z * (lp - l1);
    }
    {
      const float lp = fmaxf(__logf(p.w), -100.0f);
      const float l1 = fmaxf(__logf(1.0f - p.w), -100.0f);
      acc += l1 + t.w * (lp - l1);
    }
  }

  // wave(64) shuffle reduction
  #pragma unroll
  for (int off = 32; off > 0; off >>= 1) acc += __shfl_down(acc, off, 64);

  __shared__ float smem[4];  // 256 threads = 4 waves
  const int lane = threadIdx.x & 63;
  const int wv = threadIdx.x >> 6;
  if (lane == 0) smem[wv] = acc;
  __syncthreads();
  if (threadIdx.x == 0) {
    const float blocksum = smem[0] + smem[1] + smem[2] + smem[3];
    partials[blockIdx.x] = -w * blocksum;  // plain store, no atomic
  }
}

__global__ __launch_bounds__(256) void bce_final_kernel(
    const float* __restrict__ weight, const float* __restrict__ partials,
    float* __restrict__ out) {
  // 256 threads, 8 partials each
  float acc = 0.0f;
  #pragma unroll
  for (int k = 0; k < 8; ++k) acc += partials[k * 256 + (int)threadIdx.x];

  #pragma unroll
  for (int off = 32; off > 0; off >>= 1) acc += __shfl_down(acc, off, 64);

  __shared__ float smem[4];
  const int lane = threadIdx.x & 63;
  const int wv = threadIdx.x >> 6;
  if (lane == 0) smem[wv] = acc;
  __syncthreads();
  if (threadIdx.x == 0) {
    float sw = 0.0f;
    #pragma unroll
    for (int c = 0; c < 16; ++c) sw += weight[c];
    out[0] = (smem[0] + smem[1] + smem[2] + smem[3]) / (kPerClassN * sw);
  }
}

extern "C" void kernel_launch(void* const* d_in, const int* in_sizes, int n_in,
                              void* d_out, int out_size, void* d_ws, size_t ws_size,
                              hipStream_t stream) {
  const float4* pred = (const float4*)d_in[0];
  const float4* tru = (const float4*)d_in[1];
  const float* weight = (const float*)d_in[2];
  float* out = (float*)d_out;
  float* partials = (float*)d_ws;  // 2048 floats of scratch

  bce_reduce_kernel<<<kBlocks, 256, 0, stream>>>(pred, tru, weight, partials);
  bce_final_kernel<<<1, 256, 0, stream>>>(weight, partials, out);
}

// Round 4
// 278.299 us; speedup vs baseline: 1.0274x; 1.0026x over previous
//
#include <hip/hip_runtime.h>

// BCE with per-class weights, reduced to a scalar.
// pred,true: (B=2, C=16, D=64, H=128, W=128) fp32; weight: (16,) fp32.
// final = sum_e w[c(e)] * bce_e / (B*D*H*W * sum(w))
// Memory-bound roofline: 268 MB read -> ~43 us at 6.3 TB/s achievable.
//
// R1: block-contiguous 64KB tiles, per-block class weight in SGPR.
// R2: per-block partial stores + final kernel (atomics exonerated, ~same).
// R3: explicit double-buffered register pipeline. R0-R2 all stalled ~75%
//     on vmcnt with only ~2-4 KB/wave in flight (VGPR=32 proves the
//     compiler collapsed the unroll into load->wait->compute). Batches of
//     4 float4s per tensor, prefetch next batch while computing current:
//     8 KB/wave continuously in flight, counted vmcnt waits.

static constexpr int kTotal = 2 * 16 * 64 * 128 * 128;  // 33,554,432
static constexpr int kN4 = kTotal / 4;                  // 8,388,608 float4s
static constexpr int kBlocks = 2048;
static constexpr int kPerBlock4 = kN4 / kBlocks;        // 4096 float4s/block
static constexpr float kPerClassN = 2097152.0f;         // B*D*H*W = 2^21

__device__ __forceinline__ float bce4(const float4 p, const float4 t) {
  float s = 0.0f;
  {
    const float lp = fmaxf(__logf(p.x), -100.0f);
    const float l1 = fmaxf(__logf(1.0f - p.x), -100.0f);
    s += l1 + t.x * (lp - l1);
  }
  {
    const float lp = fmaxf(__logf(p.y), -100.0f);
    const float l1 = fmaxf(__logf(1.0f - p.y), -100.0f);
    s += l1 + t.y * (lp - l1);
  }
  {
    const float lp = fmaxf(__logf(p.z), -100.0f);
    const float l1 = fmaxf(__logf(1.0f - p.z), -100.0f);
    s += l1 + t.z * (lp - l1);
  }
  {
    const float lp = fmaxf(__logf(p.w), -100.0f);
    const float l1 = fmaxf(__logf(1.0f - p.w), -100.0f);
    s += l1 + t.w * (lp - l1);
  }
  return s;
}

__global__ __launch_bounds__(256) void bce_reduce_kernel(
    const float4* __restrict__ pred, const float4* __restrict__ tru,
    const float* __restrict__ weight, float* __restrict__ partials) {
  const int base = blockIdx.x * kPerBlock4 + (int)threadIdx.x;
  // class = (float4_index >> 18) & 15 = (blockIdx.x >> 6) & 15 (block-uniform)
  const float w = weight[(blockIdx.x >> 6) & 15];

  const float4* pp = pred + base;  // thread's k-th float4 is pp[k*256]
  const float4* tp = tru + base;

  // 16 float4s per thread = 4 batches of 4; double-buffered prefetch.
  float4 pb[2][4], tb[2][4];

  // prologue: batch 0 loads
  #pragma unroll
  for (int j = 0; j < 4; ++j) {
    pb[0][j] = pp[j * 256];
    tb[0][j] = tp[j * 256];
  }

  float acc = 0.0f;  // accumulates t*lp + (1-t)*l1 (un-negated, un-weighted)
  #pragma unroll
  for (int b = 0; b < 4; ++b) {
    const int cur = b & 1;
    const int nxt = cur ^ 1;
    if (b < 3) {  // prefetch batch b+1 while computing batch b
      const float4* pp2 = pp + (b + 1) * 1024;
      const float4* tp2 = tp + (b + 1) * 1024;
      #pragma unroll
      for (int j = 0; j < 4; ++j) {
        pb[nxt][j] = pp2[j * 256];
        tb[nxt][j] = tp2[j * 256];
      }
    }
    #pragma unroll
    for (int j = 0; j < 4; ++j) acc += bce4(pb[cur][j], tb[cur][j]);
  }

  // wave(64) shuffle reduction
  #pragma unroll
  for (int off = 32; off > 0; off >>= 1) acc += __shfl_down(acc, off, 64);

  __shared__ float smem[4];  // 256 threads = 4 waves
  const int lane = threadIdx.x & 63;
  const int wv = threadIdx.x >> 6;
  if (lane == 0) smem[wv] = acc;
  __syncthreads();
  if (threadIdx.x == 0) {
    const float blocksum = smem[0] + smem[1] + smem[2] + smem[3];
    partials[blockIdx.x] = -w * blocksum;  // plain store, no atomic
  }
}

__global__ __launch_bounds__(256) void bce_final_kernel(
    const float* __restrict__ weight, const float* __restrict__ partials,
    float* __restrict__ out) {
  float acc = 0.0f;
  #pragma unroll
  for (int k = 0; k < 8; ++k) acc += partials[k * 256 + (int)threadIdx.x];

  #pragma unroll
  for (int off = 32; off > 0; off >>= 1) acc += __shfl_down(acc, off, 64);

  __shared__ float smem[4];
  const int lane = threadIdx.x & 63;
  const int wv = threadIdx.x >> 6;
  if (lane == 0) smem[wv] = acc;
  __syncthreads();
  if (threadIdx.x == 0) {
    float sw = 0.0f;
    #pragma unroll
    for (int c = 0; c < 16; ++c) sw += weight[c];
    out[0] = (smem[0] + smem[1] + smem[2] + smem[3]) / (kPerClassN * sw);
  }
}

extern "C" void kernel_launch(void* const* d_in, const int* in_sizes, int n_in,
                              void* d_out, int out_size, void* d_ws, size_t ws_size,
                              hipStream_t stream) {
  const float4* pred = (const float4*)d_in[0];
  const float4* tru = (const float4*)d_in[1];
  const float* weight = (const float*)d_in[2];
  float* out = (float*)d_out;
  float* partials = (float*)d_ws;  // 2048 floats of scratch

  bce_reduce_kernel<<<kBlocks, 256, 0, stream>>>(pred, tru, weight, partials);
  bce_final_kernel<<<1, 256, 0, stream>>>(weight, partials, out);
}

// Round 5
// 276.538 us; speedup vs baseline: 1.0340x; 1.0064x over previous
//
#include <hip/hip_runtime.h>

// BCE with per-class weights, reduced to a scalar.
// pred,true: (B=2, C=16, D=64, H=128, W=128) fp32; weight: (16,) fp32.
// final = sum_e w[c(e)] * bce_e / (B*D*H*W * sum(w))
// Memory-bound roofline: 268 MB read -> ~43 us at 6.3 TB/s achievable.
//
// R1: block-contiguous 64KB tiles, per-block class weight in SGPR.
// R2: per-block partial stores + final kernel (atomics exonerated, ~same).
// R3: source-level double-buffer -- DEFEATED by the scheduler (VGPR stayed
//     32; loads sunk to uses; same machine loop as R1/R2).
// R4: __builtin_amdgcn_sched_barrier(0) fences around the prefetch block so
//     the scheduler CANNOT sink batch b+1's 8 float4 loads below batch b's
//     compute. Forces counted vmcnt waits + 8 KB/wave in flight.
//     Check: VGPR_Count must rise to ~80+. If it does and dur is flat,
//     the ~2.6 TB/s cap is structural (contended roofline), not latency.

static constexpr int kTotal = 2 * 16 * 64 * 128 * 128;  // 33,554,432
static constexpr int kN4 = kTotal / 4;                  // 8,388,608 float4s
static constexpr int kBlocks = 2048;
static constexpr int kPerBlock4 = kN4 / kBlocks;        // 4096 float4s/block
static constexpr float kPerClassN = 2097152.0f;         // B*D*H*W = 2^21

__device__ __forceinline__ float bce4(const float4 p, const float4 t) {
  float s = 0.0f;
  {
    const float lp = fmaxf(__logf(p.x), -100.0f);
    const float l1 = fmaxf(__logf(1.0f - p.x), -100.0f);
    s += l1 + t.x * (lp - l1);
  }
  {
    const float lp = fmaxf(__logf(p.y), -100.0f);
    const float l1 = fmaxf(__logf(1.0f - p.y), -100.0f);
    s += l1 + t.y * (lp - l1);
  }
  {
    const float lp = fmaxf(__logf(p.z), -100.0f);
    const float l1 = fmaxf(__logf(1.0f - p.z), -100.0f);
    s += l1 + t.z * (lp - l1);
  }
  {
    const float lp = fmaxf(__logf(p.w), -100.0f);
    const float l1 = fmaxf(__logf(1.0f - p.w), -100.0f);
    s += l1 + t.w * (lp - l1);
  }
  return s;
}

__global__ __launch_bounds__(256) void bce_reduce_kernel(
    const float4* __restrict__ pred, const float4* __restrict__ tru,
    const float* __restrict__ weight, float* __restrict__ partials) {
  const int base = blockIdx.x * kPerBlock4 + (int)threadIdx.x;
  // class = (float4_index >> 18) & 15 = (blockIdx.x >> 6) & 15 (block-uniform)
  const float w = weight[(blockIdx.x >> 6) & 15];

  const float4* pp = pred + base;  // thread's k-th float4 is pp[k*256]
  const float4* tp = tru + base;

  // 16 float4s per thread = 4 batches of 4; double-buffered prefetch,
  // schedule pinned with sched_barrier so loads CANNOT sink below compute.
  float4 pb[2][4], tb[2][4];

  #pragma unroll
  for (int j = 0; j < 4; ++j) {
    pb[0][j] = pp[j * 256];
    tb[0][j] = tp[j * 256];
  }

  float acc0 = 0.0f, acc1 = 0.0f;
  #pragma unroll
  for (int b = 0; b < 4; ++b) {
    const int cur = b & 1;
    const int nxt = cur ^ 1;
    if (b < 3) {  // prefetch batch b+1; fences pin these loads HERE
      const float4* pp2 = pp + (b + 1) * 1024;
      const float4* tp2 = tp + (b + 1) * 1024;
      __builtin_amdgcn_sched_barrier(0);
      #pragma unroll
      for (int j = 0; j < 4; ++j) {
        pb[nxt][j] = pp2[j * 256];
        tb[nxt][j] = tp2[j * 256];
      }
      __builtin_amdgcn_sched_barrier(0);
    }
    acc0 += bce4(pb[cur][0], tb[cur][0]);
    acc1 += bce4(pb[cur][1], tb[cur][1]);
    acc0 += bce4(pb[cur][2], tb[cur][2]);
    acc1 += bce4(pb[cur][3], tb[cur][3]);
  }
  float acc = acc0 + acc1;

  // wave(64) shuffle reduction
  #pragma unroll
  for (int off = 32; off > 0; off >>= 1) acc += __shfl_down(acc, off, 64);

  __shared__ float smem[4];  // 256 threads = 4 waves
  const int lane = threadIdx.x & 63;
  const int wv = threadIdx.x >> 6;
  if (lane == 0) smem[wv] = acc;
  __syncthreads();
  if (threadIdx.x == 0) {
    const float blocksum = smem[0] + smem[1] + smem[2] + smem[3];
    partials[blockIdx.x] = -w * blocksum;  // plain store, no atomic
  }
}

__global__ __launch_bounds__(256) void bce_final_kernel(
    const float* __restrict__ weight, const float* __restrict__ partials,
    float* __restrict__ out) {
  float acc = 0.0f;
  #pragma unroll
  for (int k = 0; k < 8; ++k) acc += partials[k * 256 + (int)threadIdx.x];

  #pragma unroll
  for (int off = 32; off > 0; off >>= 1) acc += __shfl_down(acc, off, 64);

  __shared__ float smem[4];
  const int lane = threadIdx.x & 63;
  const int wv = threadIdx.x >> 6;
  if (lane == 0) smem[wv] = acc;
  __syncthreads();
  if (threadIdx.x == 0) {
    float sw = 0.0f;
    #pragma unroll
    for (int c = 0; c < 16; ++c) sw += weight[c];
    out[0] = (smem[0] + smem[1] + smem[2] + smem[3]) / (kPerClassN * sw);
  }
}

extern "C" void kernel_launch(void* const* d_in, const int* in_sizes, int n_in,
                              void* d_out, int out_size, void* d_ws, size_t ws_size,
                              hipStream_t stream) {
  const float4* pred = (const float4*)d_in[0];
  const float4* tru = (const float4*)d_in[1];
  const float* weight = (const float*)d_in[2];
  float* out = (float*)d_out;
  float* partials = (float*)d_ws;  // 2048 floats of scratch

  bce_reduce_kernel<<<kBlocks, 256, 0, stream>>>(pred, tru, weight, partials);
  bce_final_kernel<<<1, 256, 0, stream>>>(weight, partials, out);
}

// Round 6
// 272.917 us; speedup vs baseline: 1.0477x; 1.0133x over previous
//
#include <hip/hip_runtime.h>

// BCE with per-class weights, reduced to a scalar.
// pred,true: (B=2, C=16, D=64, H=128, W=128) fp32; weight: (16,) fp32.
// final = sum_e w[c(e)] * bce_e / (B*D*H*W * sum(w))
// Memory-bound roofline: 268 MB read -> ~43 us at 6.3 TB/s achievable;
// observed environment: ~half the input is L3-resident (harness restore),
// HBM delivers ~1.3 TB/s, combined ~2.6 TB/s -> ~103 us floor seen R0-R4.
//
// R1-R4 history: block tiles, no atomics, double-buffer, sched_barrier --
// all compiled to the same load->vmcnt(0)->compute round-trip loop, all
// ~103-107 us. The compiler cannot be made to pipeline this loop.
// R5: eliminate the loop. ONE float4-pair per thread (32768 blocks x 256).
// Both loads feed the single compute block, so the scheduler has nothing
// to sink: every load in the kernel is independent, MLP comes from wave
// retirement + continuous workgroup launch instead of in-wave pipelining.
// Decisive: flat duration => memory path is capped; contended roofline.

static constexpr int kTotal = 2 * 16 * 64 * 128 * 128;  // 33,554,432
static constexpr int kN4 = kTotal / 4;                  // 8,388,608 float4s
static constexpr int kBlocks = kN4 / 256;               // 32768 blocks
static constexpr float kPerClassN = 2097152.0f;         // B*D*H*W = 2^21

__global__ __launch_bounds__(256) void bce_reduce_kernel(
    const float4* __restrict__ pred, const float4* __restrict__ tru,
    const float* __restrict__ weight, float* __restrict__ partials) {
  const int i = blockIdx.x * 256 + (int)threadIdx.x;
  // class = (float4_index >> 18) & 15 = (blockIdx.x >> 10) & 15 (block-uniform)
  const float w = weight[(blockIdx.x >> 10) & 15];

  const float4 p = pred[i];
  const float4 t = tru[i];

  float acc = 0.0f;  // t*lp + (1-t)*l1 (un-negated, un-weighted)
  {
    const float lp = fmaxf(__logf(p.x), -100.0f);
    const float l1 = fmaxf(__logf(1.0f - p.x), -100.0f);
    acc += l1 + t.x * (lp - l1);
  }
  {
    const float lp = fmaxf(__logf(p.y), -100.0f);
    const float l1 = fmaxf(__logf(1.0f - p.y), -100.0f);
    acc += l1 + t.y * (lp - l1);
  }
  {
    const float lp = fmaxf(__logf(p.z), -100.0f);
    const float l1 = fmaxf(__logf(1.0f - p.z), -100.0f);
    acc += l1 + t.z * (lp - l1);
  }
  {
    const float lp = fmaxf(__logf(p.w), -100.0f);
    const float l1 = fmaxf(__logf(1.0f - p.w), -100.0f);
    acc += l1 + t.w * (lp - l1);
  }

  // wave(64) shuffle reduction
  #pragma unroll
  for (int off = 32; off > 0; off >>= 1) acc += __shfl_down(acc, off, 64);

  __shared__ float smem[4];  // 256 threads = 4 waves
  const int lane = threadIdx.x & 63;
  const int wv = threadIdx.x >> 6;
  if (lane == 0) smem[wv] = acc;
  __syncthreads();
  if (threadIdx.x == 0) {
    const float blocksum = smem[0] + smem[1] + smem[2] + smem[3];
    partials[blockIdx.x] = -w * blocksum;  // plain store, no atomic
  }
}

__global__ __launch_bounds__(256) void bce_final_kernel(
    const float* __restrict__ weight, const float* __restrict__ partials,
    float* __restrict__ out) {
  // 32768 partials, 256 threads -> 128 each
  float acc = 0.0f;
  #pragma unroll 8
  for (int k = 0; k < 128; ++k) acc += partials[k * 256 + (int)threadIdx.x];

  #pragma unroll
  for (int off = 32; off > 0; off >>= 1) acc += __shfl_down(acc, off, 64);

  __shared__ float smem[4];
  const int lane = threadIdx.x & 63;
  const int wv = threadIdx.x >> 6;
  if (lane == 0) smem[wv] = acc;
  __syncthreads();
  if (threadIdx.x == 0) {
    float sw = 0.0f;
    #pragma unroll
    for (int c = 0; c < 16; ++c) sw += weight[c];
    out[0] = (smem[0] + smem[1] + smem[2] + smem[3]) / (kPerClassN * sw);
  }
}

extern "C" void kernel_launch(void* const* d_in, const int* in_sizes, int n_in,
                              void* d_out, int out_size, void* d_ws, size_t ws_size,
                              hipStream_t stream) {
  const float4* pred = (const float4*)d_in[0];
  const float4* tru = (const float4*)d_in[1];
  const float* weight = (const float*)d_in[2];
  float* out = (float*)d_out;
  float* partials = (float*)d_ws;  // 32768 floats = 128 KB of scratch (ws)

  bce_reduce_kernel<<<kBlocks, 256, 0, stream>>>(pred, tru, weight, partials);
  bce_final_kernel<<<1, 256, 0, stream>>>(weight, partials, out);
}